// Round 9
// baseline (106.365 us; speedup 1.0000x reference)
//
#include <hip/hip_runtime.h>
#include <math.h>

#define NB 4
#define NC 128
#define NH 128
#define NW 128
#define NHW (NH*NW)
#define NCOUT 128

// ws float offsets
#define SY_OFF 0
#define SX_OFF 1179648
#define MK_OFF 2359296
#define WOFF_OFF 3538944    // 36 slabs [64][36] bf16 (offset-conv W) = 82944 shorts
#define WMAIN_OFF 3580416   // 36 slabs [128][32] bf16 (main W) = 147456 shorts
#define XT_OFF 3663360      // bf16 xT[b][cg16][y][x][8ch] : 8388608 shorts
// total ws use: ~31.4 MB

typedef short short8 __attribute__((ext_vector_type(8)));
typedef float f32x4 __attribute__((ext_vector_type(4)));

__device__ inline short f2bf(float f) {
    unsigned u = __float_as_uint(f);
    u = (u + 0x7FFFu + ((u >> 16) & 1u)) >> 16;   // RNE
    return (short)u;
}
__device__ inline unsigned pack2(float lo, float hi) {
    unsigned r;
    asm("v_cvt_pk_bf16_f32 %0, %1, %2" : "=v"(r) : "v"(lo), "v"(hi));
    return r;
}
__device__ inline float bflo(unsigned u) { return __uint_as_float(u << 16); }
__device__ inline float bfhi(unsigned u) { return __uint_as_float(u & 0xffff0000u); }

__device__ inline void gload_lds16(const void* g, void* l) {
    __builtin_amdgcn_global_load_lds(
        (const __attribute__((address_space(1))) unsigned int*)g,
        (__attribute__((address_space(3))) unsigned int*)l, 16, 0, 0);
}

// ---------------------------------------------------------------------------
// wtrans: offset table 36 slabs [64][36] (padded) + main table 36 slabs [128][32]
// ---------------------------------------------------------------------------
__global__ void wtrans_kernel(const float* __restrict__ w_off,
                              const float* __restrict__ weight,
                              float* __restrict__ ws)
{
    int i = blockIdx.x * 256 + threadIdx.x;
    if (i < 36*2304) {
        int s = i / 2304, rem = i - s*2304;
        int row = rem / 36, c = rem - row*36;
        int chunk = s / 9, k2 = s - 9*chunk;
        float v = (row < 54 && c < 32) ? w_off[(row*NC + chunk*32 + c)*9 + k2] : 0.f;
        ((short*)(ws + WOFF_OFF))[i] = f2bf(v);
    } else if (i < 36*2304 + 36*4096) {
        int j = i - 36*2304;
        int s = j >> 12, rem = j & 4095;
        int row = rem >> 5, c = rem & 31;
        int chunk = s / 9, k2 = s - 9*chunk;
        ((short*)(ws + WMAIN_OFF))[j] = f2bf(weight[(row*NC + chunk*32 + c)*9 + k2]);
    }
}

// ---------------------------------------------------------------------------
// xtrans: x NCHW fp32 -> xT[b][cg][y][x][8ch] bf16. Pure BW.
// ---------------------------------------------------------------------------
__global__ __launch_bounds__(256) void xtrans_kernel(
    const float* __restrict__ x, float* __restrict__ ws)
{
    short* xT = (short*)(ws + XT_OFF);
    const int bid = blockIdx.x;
    const int ys = bid & 15, cg = (bid >> 4) & 15, b = bid >> 8;
    const int col = threadIdx.x & 127, rr = threadIdx.x >> 7;
    const float* xb = x + ((long)(b*NC + cg*8))*NHW;
#pragma unroll
    for (int yy = 0; yy < 4; ++yy) {
        const int y = ys*8 + yy*2 + rr;
        const float* p = xb + y*NW + col;
        float v[8];
#pragma unroll
        for (int q = 0; q < 8; ++q) v[q] = p[q*NHW];
        uint4 u = make_uint4(pack2(v[0],v[1]), pack2(v[2],v[3]),
                             pack2(v[4],v[5]), pack2(v[6],v[7]));
        *(uint4*)&xT[(((long)(b*16+cg)*NH + y)*NW + col)*8] = u;
    }
}

// ---------------------------------------------------------------------------
// offconv: 3x3 conv (54 ch pad 64) as pure GEMM over xT.
// Block = (b, ho): 128 px x 64 cout, 512 threads = 8 waves.
// ---------------------------------------------------------------------------
__global__ __launch_bounds__(512, 4) void offconv_kernel(
    float* __restrict__ ws, const float* __restrict__ b_off)
{
    __shared__ short wslab[2][2304];    // [64][36], 4608 B each
    int bid = blockIdx.x;
    bid = (bid & 7) * 64 + (bid >> 3);      // XCD swizzle (512 = 8*64)
    const int b   = bid >> 7;
    const int ho  = bid & 127;
    const int tid = threadIdx.x;
    const int lane = tid & 63;
    const int wid = tid >> 6;
    const int n = lane & 15, g = lane >> 4;
    const int px = wid*16 + n;
    const short* woff = (const short*)(ws + WOFF_OFF);
    const char*  xTb  = (const char*)((const short*)(ws + XT_OFF) + (long)b*16*NHW*8);

    f32x4 acc[4];
#pragma unroll
    for (int rf = 0; rf < 4; ++rf) acc[rf] = (f32x4){0.f,0.f,0.f,0.f};

    auto DMA = [&](int it, int buf) {
        if (tid < 288) gload_lds16(woff + it*2304 + tid*8, &wslab[buf][tid*8]);
    };
    auto LOADB = [&](int it) -> short8 {
        const int chunk = it/9, k2 = it - 9*chunk;
        const int y = ho + k2/3 - 1, xc = px + (k2%3) - 1;
        short8 bf = (short8){0,0,0,0,0,0,0,0};
        if ((unsigned)y < NH && (unsigned)xc < NW)
            bf = *(const short8*)(xTb + ((long)(chunk*4 + g)*NHW + y*NW + xc)*16);
        return bf;
    };

    DMA(0, 0);
    short8 bcur = LOADB(0);
    __syncthreads();

#pragma unroll 1
    for (int it = 0; it < 36; ++it) {
        const int cur = it & 1, nxt = cur ^ 1;
        short8 bnext;
        if (it < 35) { DMA(it+1, nxt); bnext = LOADB(it+1); }
        __builtin_amdgcn_sched_barrier(0);
#pragma unroll
        for (int rf = 0; rf < 4; ++rf) {
            short8 af = *(const short8*)&wslab[cur][(rf*16 + n)*36 + 8*g];
            acc[rf] = __builtin_amdgcn_mfma_f32_16x16x32_bf16(af, bcur, acc[rf], 0,0,0);
        }
        __syncthreads();
        bcur = bnext;
    }

    // epilogue: route channels -> processed sy/sx/mask
#pragma unroll
    for (int rf = 0; rf < 4; ++rf) {
#pragma unroll
        for (int r = 0; r < 4; ++r) {
            int cout = 16*rf + 4*g + r;
            if (cout >= 54) continue;
            float v = acc[rf][r] + b_off[cout];
            if (cout < 36) {
                int og = cout / 18, rem = cout - 18*og;
                int k2c = rem >> 1, d = cout & 1;
                float base = d ? (float)(px - 1 + (k2c % 3))
                              : (float)(ho - 1 + (k2c / 3));
                ws[(d ? SX_OFF : SY_OFF) + (((b*2+og)*9 + k2c)*NHW) + ho*NW + px] = v + base;
            } else {
                int cc = cout - 36;
                int og = cc / 9, k2c = cc - 9*og;
                ws[MK_OFF + (((b*2+og)*9 + k2c)*NHW) + ho*NW + px] = 1.f/(1.f+expf(-v));
            }
        }
    }
}

// ---------------------------------------------------------------------------
// deform: block = (b, ho, half-row): 64 px x 128 cout, 256 threads = 4 waves.
// 1024 blocks -> 4 independent blocks/CU (fills barrier-drain stalls).
// A-fragments prefetched to REGISTERS from global (L1-hot 8KB slabs) — no DMA.
// Gathers from xT[b][cg][y][x][8ch] prefetched one iter ahead.
// ---------------------------------------------------------------------------
__global__ __launch_bounds__(256, 4) void deform_kernel(
    const float* __restrict__ ws_c, float* __restrict__ ws,
    const float* __restrict__ bias, float* __restrict__ out)
{
    __shared__ short4 pI[9][64];          // 4608 B (element offsets)
    __shared__ float4 pW[9][64];          // 9216 B
    __shared__ short  vals[2][64][40];    // 10240 B

    int bid = blockIdx.x;
    bid = (bid & 7) * 128 + (bid >> 3);     // XCD swizzle (1024 = 8*128)
    const int b   = bid >> 8;
    const int ho  = (bid >> 1) & 127;
    const int wb  = (bid & 1) * 64;
    const int tid = threadIdx.x;
    const int lane = tid & 63;
    const int wid = tid >> 6;               // 0..3
    const int n = lane & 15, g = lane >> 4;
    const int ch  = wid & 1;                // cout half (MFMA role)
    const int pxh = wid >> 1;               // px half of 32 (MFMA role)
    const int sp  = tid & 63;               // pixel 0..63 (sampling role)
    const int sub = tid >> 6;               // 8-ch group (sampling role)
    const short* wmn = (const short*)(ws + WMAIN_OFF);
    const char*  xTb = (const char*)((const short*)(ws + XT_OFF) + (long)b*16*NHW*8);

    f32x4 acc[4][2];
#pragma unroll
    for (int rf = 0; rf < 4; ++rf) {
        acc[rf][0] = (f32x4){0.f,0.f,0.f,0.f};
        acc[rf][1] = (f32x4){0.f,0.f,0.f,0.f};
    }

    auto FIN = [&](const uint4& A, const uint4& Bc, const uint4& Cc, const uint4& D,
                   const float4& Wv, int buf) {
        uint4 u; unsigned* up = (unsigned*)&u;
        const unsigned* a = (const unsigned*)&A;
        const unsigned* bq = (const unsigned*)&Bc;
        const unsigned* c = (const unsigned*)&Cc;
        const unsigned* d = (const unsigned*)&D;
#pragma unroll
        for (int e = 0; e < 4; ++e) {
            float lo = Wv.x*bflo(a[e]) + Wv.y*bflo(bq[e]) + Wv.z*bflo(c[e]) + Wv.w*bflo(d[e]);
            float hi = Wv.x*bfhi(a[e]) + Wv.y*bfhi(bq[e]) + Wv.z*bfhi(c[e]) + Wv.w*bfhi(d[e]);
            up[e] = pack2(lo, hi);
        }
        *(uint4*)&vals[buf][sp][sub*8] = u;
    };

    short8 acur0, acur1, acur2, acur3;
    #define LOADA(dst, it, rf) \
        dst = *(const short8*)(wmn + (it)*4096 + (ch*64 + (rf)*16 + n)*32 + 8*g)

#pragma unroll 1
    for (int og = 0; og < 2; ++og) {
        const int it0 = og*18;
        if (og) __syncthreads();
        // ---- build bilinear params for this og (64 px of this block)
        for (int e = tid; e < 576; e += 256) {
            const int k2 = e >> 6, px = e & 63;
            const int sidx = (((b*2+og)*9 + k2)*NHW) + ho*NW + wb + px;
            const float sy = ws[SY_OFF + sidx];
            const float sx = ws[SX_OFF + sidx];
            const float m  = ws[MK_OFF + sidx];
            const float y0f = floorf(sy), x0f = floorf(sx);
            const float ly = sy - y0f, lx = sx - x0f;
            const int y0 = (int)y0f, x0i = (int)x0f;
            const int y1 = y0 + 1, x1 = x0i + 1;
            const bool vy0 = (unsigned)y0 < NH, vy1 = (unsigned)y1 < NH;
            const bool vx0 = (unsigned)x0i < NW, vx1 = (unsigned)x1 < NW;
            const int cy0 = min(max(y0,0),NH-1), cy1 = min(max(y1,0),NH-1);
            const int cx0 = min(max(x0i,0),NW-1), cx1 = min(max(x1,0),NW-1);
            pI[k2][px] = make_short4((short)(cy0*NW + cx0), (short)(cy0*NW + cx1),
                                     (short)(cy1*NW + cx0), (short)(cy1*NW + cx1));
            pW[k2][px] = make_float4(
                (vy0 && vx0) ? (1.f-ly)*(1.f-lx)*m : 0.f,
                (vy0 && vx1) ? (1.f-ly)*lx*m       : 0.f,
                (vy1 && vx0) ? ly*(1.f-lx)*m       : 0.f,
                (vy1 && vx1) ? ly*lx*m             : 0.f);
        }
        __syncthreads();

        // prologue: A(it0) (og0 only; og1 inherits from prefetch) + sample(it0)
        if (og == 0) {
            LOADA(acur0, 0, 0); LOADA(acur1, 0, 1);
            LOADA(acur2, 0, 2); LOADA(acur3, 0, 3);
        }
        {
            const int chunk = it0/9, k2n = it0 - 9*chunk;
            const short4 I = pI[k2n][sp];
            const float4 Wv = pW[k2n][sp];
            const char* xp = xTb + (long)(chunk*4 + sub)*(NHW*16);
            uint4 A  = *(const uint4*)(xp + (((int)I.x) << 4));
            uint4 Bc = *(const uint4*)(xp + (((int)I.y) << 4));
            uint4 Cc = *(const uint4*)(xp + (((int)I.z) << 4));
            uint4 D  = *(const uint4*)(xp + (((int)I.w) << 4));
            FIN(A, Bc, Cc, D, Wv, 0);
        }
        __syncthreads();

#pragma unroll 1
        for (int it = it0; it < it0 + 18; ++it) {
            const int cur = it & 1, nxt = cur ^ 1;
            const bool pre = (it < it0 + 17);

            short8 anxt0, anxt1, anxt2, anxt3;
            uint4 A, Bc, Cc, D;
            float4 Wv;
            if (it < 35) {
                LOADA(anxt0, it+1, 0); LOADA(anxt1, it+1, 1);
                LOADA(anxt2, it+1, 2); LOADA(anxt3, it+1, 3);
            }
            if (pre) {
                const int itn = it + 1;
                const int chunk = itn/9, k2n = itn - 9*chunk;
                const short4 I = pI[k2n][sp];
                Wv = pW[k2n][sp];
                const char* xp = xTb + (long)(chunk*4 + sub)*(NHW*16);
                A  = *(const uint4*)(xp + (((int)I.x) << 4));
                Bc = *(const uint4*)(xp + (((int)I.y) << 4));
                Cc = *(const uint4*)(xp + (((int)I.z) << 4));
                D  = *(const uint4*)(xp + (((int)I.w) << 4));
            }
            __builtin_amdgcn_sched_barrier(0);

            // ---- MFMA from LDS B + register A (K=32)
            {
                short8 bf0 = *(const short8*)&vals[cur][pxh*32 + n][8*g];
                short8 bf1 = *(const short8*)&vals[cur][pxh*32 + 16 + n][8*g];
                acc[0][0] = __builtin_amdgcn_mfma_f32_16x16x32_bf16(acur0, bf0, acc[0][0], 0,0,0);
                acc[0][1] = __builtin_amdgcn_mfma_f32_16x16x32_bf16(acur0, bf1, acc[0][1], 0,0,0);
                acc[1][0] = __builtin_amdgcn_mfma_f32_16x16x32_bf16(acur1, bf0, acc[1][0], 0,0,0);
                acc[1][1] = __builtin_amdgcn_mfma_f32_16x16x32_bf16(acur1, bf1, acc[1][1], 0,0,0);
                acc[2][0] = __builtin_amdgcn_mfma_f32_16x16x32_bf16(acur2, bf0, acc[2][0], 0,0,0);
                acc[2][1] = __builtin_amdgcn_mfma_f32_16x16x32_bf16(acur2, bf1, acc[2][1], 0,0,0);
                acc[3][0] = __builtin_amdgcn_mfma_f32_16x16x32_bf16(acur3, bf0, acc[3][0], 0,0,0);
                acc[3][1] = __builtin_amdgcn_mfma_f32_16x16x32_bf16(acur3, bf1, acc[3][1], 0,0,0);
            }
            __builtin_amdgcn_sched_barrier(0);

            if (pre) FIN(A, Bc, Cc, D, Wv, nxt);
            __syncthreads();
            acur0 = anxt0; acur1 = anxt1; acur2 = anxt2; acur3 = anxt3;
        }
    }

    // ---- epilogue
#pragma unroll
    for (int rf = 0; rf < 4; ++rf) {
#pragma unroll
        for (int pxb = 0; pxb < 2; ++pxb) {
            const int px = wb + pxh*32 + pxb*16 + n;
#pragma unroll
            for (int r = 0; r < 4; ++r) {
                const int cout = ch*64 + rf*16 + 4*g + r;
                out[((b*NCOUT + cout)*NH + ho)*NW + px] = acc[rf][pxb][r] + bias[cout];
            }
        }
    }
    #undef LOADA
}

// ---------------------------------------------------------------------------
extern "C" void kernel_launch(void* const* d_in, const int* in_sizes, int n_in,
                              void* d_out, int out_size, void* d_ws, size_t ws_size,
                              hipStream_t stream)
{
    const float* x      = (const float*)d_in[0];
    const float* w_off  = (const float*)d_in[1];
    const float* b_off  = (const float*)d_in[2];
    const float* weight = (const float*)d_in[3];
    const float* bias   = (const float*)d_in[4];
    float* out = (float*)d_out;
    float* ws  = (float*)d_ws;

    hipLaunchKernelGGL(wtrans_kernel, dim3(900), dim3(256), 0, stream,
                       w_off, weight, ws);
    hipLaunchKernelGGL(xtrans_kernel, dim3(1024), dim3(256), 0, stream,
                       x, ws);
    hipLaunchKernelGGL(offconv_kernel, dim3(NB*NH), dim3(512), 0, stream,
                       ws, b_off);
    hipLaunchKernelGGL(deform_kernel, dim3(NB*NH*2), dim3(256), 0, stream,
                       ws, ws, bias, out);
}

// Round 11
// 92.578 us; speedup vs baseline: 1.1489x; 1.1489x over previous
//
#include <hip/hip_runtime.h>
#include <math.h>

#define NB 4
#define NC 128
#define NH 128
#define NW 128
#define NHW (NH*NW)
#define NCOUT 128

// ws float offsets
#define SY_OFF 0
#define SX_OFF 1179648
#define MK_OFF 2359296
#define WOFF_OFF 3538944    // 36 slabs [64][36] bf16 (offset-conv W)
#define WMAIN_OFF 3580416   // 36 slabs [128][36] bf16 (main W) = 165888 shorts
#define XT_OFF 3663360      // bf16 xT[b][cg16][y][x][8ch] : 8388608 shorts

typedef short short8 __attribute__((ext_vector_type(8)));
typedef float f32x4 __attribute__((ext_vector_type(4)));

__device__ inline short f2bf(float f) {
    unsigned u = __float_as_uint(f);
    u = (u + 0x7FFFu + ((u >> 16) & 1u)) >> 16;   // RNE
    return (short)u;
}
__device__ inline unsigned pack2(float lo, float hi) {
    unsigned r;
    asm("v_cvt_pk_bf16_f32 %0, %1, %2" : "=v"(r) : "v"(lo), "v"(hi));
    return r;
}
__device__ inline float bflo(unsigned u) { return __uint_as_float(u << 16); }
__device__ inline float bfhi(unsigned u) { return __uint_as_float(u & 0xffff0000u); }
__device__ inline unsigned pkf16(float a, float b) {
    auto h = __builtin_amdgcn_cvt_pkrtz(a, b);   // __fp16 ext_vector(2)
    unsigned r; __builtin_memcpy(&r, &h, 4); return r;
}
__device__ inline float f16f(unsigned s) {
    unsigned short us = (unsigned short)s;
    __fp16 h; __builtin_memcpy(&h, &us, 2); return (float)h;
}
__device__ inline void gload_lds16(const void* g, void* l) {
    __builtin_amdgcn_global_load_lds(
        (const __attribute__((address_space(1))) unsigned int*)g,
        (__attribute__((address_space(3))) unsigned int*)l, 16, 0, 0);
}

// ---------------------------------------------------------------------------
// wtrans: offset table 36 slabs [64][36] + main table 36 slabs [128][36] padded
// ---------------------------------------------------------------------------
__global__ void wtrans_kernel(const float* __restrict__ w_off,
                              const float* __restrict__ weight,
                              float* __restrict__ ws)
{
    int i = blockIdx.x * 256 + threadIdx.x;
    if (i < 36*2304) {
        int s = i / 2304, rem = i - s*2304;
        int row = rem / 36, c = rem - row*36;
        int chunk = s / 9, k2 = s - 9*chunk;
        float v = (row < 54 && c < 32) ? w_off[(row*NC + chunk*32 + c)*9 + k2] : 0.f;
        ((short*)(ws + WOFF_OFF))[i] = f2bf(v);
    } else if (i < 36*2304 + 36*4608) {
        int j = i - 36*2304;
        int s = j / 4608, rem = j - s*4608;
        int row = rem / 36, c = rem - row*36;
        int chunk = s / 9, k2 = s - 9*chunk;
        float v = (c < 32) ? weight[(row*NC + chunk*32 + c)*9 + k2] : 0.f;
        ((short*)(ws + WMAIN_OFF))[j] = f2bf(v);
    }
}

// ---------------------------------------------------------------------------
// xtrans: x NCHW fp32 -> xT[b][cg][y][x][8ch] bf16. Pure BW.
// ---------------------------------------------------------------------------
__global__ __launch_bounds__(256) void xtrans_kernel(
    const float* __restrict__ x, float* __restrict__ ws)
{
    short* xT = (short*)(ws + XT_OFF);
    const int bid = blockIdx.x;
    const int ys = bid & 15, cg = (bid >> 4) & 15, b = bid >> 8;
    const int col = threadIdx.x & 127, rr = threadIdx.x >> 7;
    const float* xb = x + ((long)(b*NC + cg*8))*NHW;
#pragma unroll
    for (int yy = 0; yy < 4; ++yy) {
        const int y = ys*8 + yy*2 + rr;
        const float* p = xb + y*NW + col;
        float v[8];
#pragma unroll
        for (int q = 0; q < 8; ++q) v[q] = p[q*NHW];
        uint4 u = make_uint4(pack2(v[0],v[1]), pack2(v[2],v[3]),
                             pack2(v[4],v[5]), pack2(v[6],v[7]));
        *(uint4*)&xT[(((long)(b*16+cg)*NH + y)*NW + col)*8] = u;
    }
}

// ---------------------------------------------------------------------------
// offconv: 3x3 conv (54 ch pad 64) as pure GEMM over xT. (R8 structure)
// ---------------------------------------------------------------------------
__global__ __launch_bounds__(512, 4) void offconv_kernel(
    float* __restrict__ ws, const float* __restrict__ b_off)
{
    __shared__ short wslab[2][2304];
    int bid = blockIdx.x;
    bid = (bid & 7) * 64 + (bid >> 3);      // XCD swizzle
    const int b   = bid >> 7;
    const int ho  = bid & 127;
    const int tid = threadIdx.x;
    const int lane = tid & 63;
    const int wid = tid >> 6;
    const int n = lane & 15, g = lane >> 4;
    const int px = wid*16 + n;
    const short* woff = (const short*)(ws + WOFF_OFF);
    const char*  xTb  = (const char*)((const short*)(ws + XT_OFF) + (long)b*16*NHW*8);

    f32x4 acc[4];
#pragma unroll
    for (int rf = 0; rf < 4; ++rf) acc[rf] = (f32x4){0.f,0.f,0.f,0.f};

    auto DMA = [&](int it, int buf) {
        if (tid < 288) gload_lds16(woff + it*2304 + tid*8, &wslab[buf][tid*8]);
    };
    auto LOADB = [&](int it) -> short8 {
        const int chunk = it/9, k2 = it - 9*chunk;
        const int y = ho + k2/3 - 1, xc = px + (k2%3) - 1;
        short8 bf = (short8){0,0,0,0,0,0,0,0};
        if ((unsigned)y < NH && (unsigned)xc < NW)
            bf = *(const short8*)(xTb + ((long)(chunk*4 + g)*NHW + y*NW + xc)*16);
        return bf;
    };

    DMA(0, 0);
    short8 bcur = LOADB(0);
    __syncthreads();

#pragma unroll 1
    for (int it = 0; it < 36; ++it) {
        const int cur = it & 1, nxt = cur ^ 1;
        short8 bnext;
        if (it < 35) { DMA(it+1, nxt); bnext = LOADB(it+1); }
        __builtin_amdgcn_sched_barrier(0);
#pragma unroll
        for (int rf = 0; rf < 4; ++rf) {
            short8 af = *(const short8*)&wslab[cur][(rf*16 + n)*36 + 8*g];
            acc[rf] = __builtin_amdgcn_mfma_f32_16x16x32_bf16(af, bcur, acc[rf], 0,0,0);
        }
        __syncthreads();
        bcur = bnext;
    }

#pragma unroll
    for (int rf = 0; rf < 4; ++rf) {
#pragma unroll
        for (int r = 0; r < 4; ++r) {
            int cout = 16*rf + 4*g + r;
            if (cout >= 54) continue;
            float v = acc[rf][r] + b_off[cout];
            if (cout < 36) {
                int og = cout / 18, rem = cout - 18*og;
                int k2c = rem >> 1, d = cout & 1;
                float base = d ? (float)(px - 1 + (k2c % 3))
                              : (float)(ho - 1 + (k2c / 3));
                ws[(d ? SX_OFF : SY_OFF) + (((b*2+og)*9 + k2c)*NHW) + ho*NW + px] = v + base;
            } else {
                int cc = cout - 36;
                int og = cc / 9, k2c = cc - 9*og;
                ws[MK_OFF + (((b*2+og)*9 + k2c)*NHW) + ho*NW + px] = 1.f/(1.f+expf(-v));
            }
        }
    }
}

// ---------------------------------------------------------------------------
// deform: block = (b, ho): 128 px x 128 cout, 512 threads = 8 waves.
// Params for BOTH og prebuilt (pI short4, pW f16x4). 2-deep gather prefetch.
// Raw s_barrier with counted vmcnt(4): DMA drained, gathers stay in flight.
// ---------------------------------------------------------------------------
__global__ __launch_bounds__(512, 4) void deform_kernel(
    const float* __restrict__ ws_c, float* __restrict__ ws,
    const float* __restrict__ bias, float* __restrict__ out)
{
    __shared__ short4 pI[18][128];        // 18432 B (element offsets)
    __shared__ uint2  pWp[18][128];       // 18432 B (4 x f16 weights)
    __shared__ short  vals[2][128][40];   // 20480 B
    __shared__ short  wslab[2][4608];     // 18432 B, [128][36] padded rows

    int bid = blockIdx.x;
    bid = (bid & 7) * 64 + (bid >> 3);      // XCD swizzle (512 = 8*64)
    const int b   = bid >> 7;
    const int ho  = bid & 127;
    const int tid = threadIdx.x;
    const int lane = tid & 63;
    const int wid = tid >> 6;               // 0..7
    const int n = lane & 15, g = lane >> 4;
    const int ch  = wid & 1;                // cout half (MFMA role)
    const int pxq = wid >> 1;               // px quarter (MFMA role)
    const int sp  = tid & 127;              // pixel (sampling role)
    const int sub = tid >> 7;               // 8-ch group (sampling role)
    const short* wmn = (const short*)(ws + WMAIN_OFF);
    const char*  xTb = (const char*)((const short*)(ws + XT_OFF) + (long)b*16*NHW*8);

    f32x4 acc[4][2];
#pragma unroll
    for (int rf = 0; rf < 4; ++rf) {
        acc[rf][0] = (f32x4){0.f,0.f,0.f,0.f};
        acc[rf][1] = (f32x4){0.f,0.f,0.f,0.f};
    }

    auto DMA = [&](int slabIdx, int buf) {
        const short* src = wmn + slabIdx*4608;
        gload_lds16(src + tid*8, &wslab[buf][tid*8]);
        if (tid < 64) gload_lds16(src + 4096 + tid*8, &wslab[buf][4096 + tid*8]);
    };
    // issue 4 corner gathers for iter j into G[0..3]
    auto GLOAD = [&](int j, uint4* G) {
        const int chunk = j/9;
        const int row = (j/18)*9 + (j%9);
        const short4 I = pI[row][sp];
        const char* xp = xTb + (long)(chunk*4 + sub)*(NHW*16);
        G[0] = *(const uint4*)(xp + (((int)I.x) << 4));
        G[1] = *(const uint4*)(xp + (((int)I.y) << 4));
        G[2] = *(const uint4*)(xp + (((int)I.z) << 4));
        G[3] = *(const uint4*)(xp + (((int)I.w) << 4));
    };
    // consume gathers of iter j -> vals[buf]
    auto FIN = [&](int j, uint4* G, int buf) {
        const int row = (j/18)*9 + (j%9);
        const uint2 wp = *(const uint2*)&pWp[row][sp];
        const float W0 = f16f(wp.x), W1 = f16f(wp.x >> 16);
        const float W2 = f16f(wp.y), W3 = f16f(wp.y >> 16);
        uint4 u; unsigned* up = (unsigned*)&u;
        const unsigned* a = (const unsigned*)&G[0];
        const unsigned* bq = (const unsigned*)&G[1];
        const unsigned* c = (const unsigned*)&G[2];
        const unsigned* d = (const unsigned*)&G[3];
#pragma unroll
        for (int e = 0; e < 4; ++e) {
            float lo = W0*bflo(a[e]) + W1*bflo(bq[e]) + W2*bflo(c[e]) + W3*bflo(d[e]);
            float hi = W0*bfhi(a[e]) + W1*bfhi(bq[e]) + W2*bfhi(c[e]) + W3*bfhi(d[e]);
            up[e] = pack2(lo, hi);
        }
        *(uint4*)&vals[buf][sp][sub*8] = u;
    };

    DMA(0, 0);   // overlaps param build; drained by the __syncthreads below

    // ---- build bilinear params for BOTH og halves
    for (int e = tid; e < 2304; e += 512) {
        const int og = e / 1152, rem = e - og*1152;
        const int k2 = rem >> 7, px = rem & 127;
        const int sidx = (((b*2+og)*9 + k2)*NHW) + ho*NW + px;
        const float sy = ws[SY_OFF + sidx];
        const float sx = ws[SX_OFF + sidx];
        const float m  = ws[MK_OFF + sidx];
        const float y0f = floorf(sy), x0f = floorf(sx);
        const float ly = sy - y0f, lx = sx - x0f;
        const int y0 = (int)y0f, x0i = (int)x0f;
        const int y1 = y0 + 1, x1 = x0i + 1;
        const bool vy0 = (unsigned)y0 < NH, vy1 = (unsigned)y1 < NH;
        const bool vx0 = (unsigned)x0i < NW, vx1 = (unsigned)x1 < NW;
        const int cy0 = min(max(y0,0),NH-1), cy1 = min(max(y1,0),NH-1);
        const int cx0 = min(max(x0i,0),NW-1), cx1 = min(max(x1,0),NW-1);
        pI[og*9+k2][px] = make_short4(
            (short)(cy0*NW + cx0), (short)(cy0*NW + cx1),
            (short)(cy1*NW + cx0), (short)(cy1*NW + cx1));
        const float W0 = (vy0 && vx0) ? (1.f-ly)*(1.f-lx)*m : 0.f;
        const float W1 = (vy0 && vx1) ? (1.f-ly)*lx*m       : 0.f;
        const float W2 = (vy1 && vx0) ? ly*(1.f-lx)*m       : 0.f;
        const float W3 = (vy1 && vx1) ? ly*lx*m             : 0.f;
        pWp[og*9+k2][px] = make_uint2(pkf16(W0, W1), pkf16(W2, W3));
    }
    __syncthreads();    // params ready; DMA(0) drained

    uint4 GA[4], GB[4];
    // prologue: sample(0) immediately; issue G(1)
    GLOAD(0, GA);
    FIN(0, GA, 0);                     // waits G(0)
    GLOAD(1, GB);                      // stays in flight across barrier
    asm volatile("s_waitcnt lgkmcnt(0)" ::: "memory");
    __builtin_amdgcn_s_barrier();
    __builtin_amdgcn_sched_barrier(0);

    // steady-state body: at entry G(it+1) in Gheld; issues into Gfree.
    auto BODY = [&](int it, uint4* Gfree, uint4* Gheld) {
        const int cur = it & 1, nxt = cur ^ 1;
        if (it < 35) DMA(it+1, nxt);
        if (it < 34) GLOAD(it+2, Gfree);
        __builtin_amdgcn_sched_barrier(0);
        // ---- MFMA from LDS (K=32)
        {
            short8 bf0 = *(const short8*)&vals[cur][pxq*32 + n][8*g];
            short8 bf1 = *(const short8*)&vals[cur][pxq*32 + 16 + n][8*g];
#pragma unroll
            for (int rf = 0; rf < 4; ++rf) {
                short8 af = *(const short8*)&wslab[cur][(ch*64 + rf*16 + n)*36 + 8*g];
                acc[rf][0] = __builtin_amdgcn_mfma_f32_16x16x32_bf16(af, bf0, acc[rf][0], 0,0,0);
                acc[rf][1] = __builtin_amdgcn_mfma_f32_16x16x32_bf16(af, bf1, acc[rf][1], 0,0,0);
            }
        }
        __builtin_amdgcn_sched_barrier(0);
        if (it < 35) FIN(it+1, Gheld, nxt);   // auto-waits G(it+1) only
        if (it < 34) {
            asm volatile("s_waitcnt vmcnt(4) lgkmcnt(0)" ::: "memory");  // DMA done, G(it+2) in flight
            __builtin_amdgcn_s_barrier();
            __builtin_amdgcn_sched_barrier(0);
        } else if (it == 34) {
            asm volatile("s_waitcnt vmcnt(0) lgkmcnt(0)" ::: "memory");
            __builtin_amdgcn_s_barrier();
            __builtin_amdgcn_sched_barrier(0);
        }
    };
#pragma unroll 1
    for (int t = 0; t < 18; ++t) {
        BODY(2*t,     GA, GB);
        BODY(2*t + 1, GB, GA);
    }

    // ---- epilogue
#pragma unroll
    for (int rf = 0; rf < 4; ++rf) {
#pragma unroll
        for (int pxb = 0; pxb < 2; ++pxb) {
            const int px = pxq*32 + pxb*16 + n;
#pragma unroll
            for (int r = 0; r < 4; ++r) {
                const int cout = ch*64 + rf*16 + 4*g + r;
                out[((b*NCOUT + cout)*NH + ho)*NW + px] = acc[rf][pxb][r] + bias[cout];
            }
        }
    }
}

// ---------------------------------------------------------------------------
extern "C" void kernel_launch(void* const* d_in, const int* in_sizes, int n_in,
                              void* d_out, int out_size, void* d_ws, size_t ws_size,
                              hipStream_t stream)
{
    const float* x      = (const float*)d_in[0];
    const float* w_off  = (const float*)d_in[1];
    const float* b_off  = (const float*)d_in[2];
    const float* weight = (const float*)d_in[3];
    const float* bias   = (const float*)d_in[4];
    float* out = (float*)d_out;
    float* ws  = (float*)d_ws;

    hipLaunchKernelGGL(wtrans_kernel, dim3(972), dim3(256), 0, stream,
                       w_off, weight, ws);
    hipLaunchKernelGGL(xtrans_kernel, dim3(1024), dim3(256), 0, stream,
                       x, ws);
    hipLaunchKernelGGL(offconv_kernel, dim3(NB*NH), dim3(512), 0, stream,
                       ws, b_off);
    hipLaunchKernelGGL(deform_kernel, dim3(NB*NH), dim3(512), 0, stream,
                       ws, ws, bias, out);
}